// Round 1
// baseline (349.562 us; speedup 1.0000x reference)
//
#include <hip/hip_runtime.h>
#include <hip/hip_bf16.h>

// Problem constants (reference: Edges GNN message MLP)
#define FEAT     64
#define NMU      100
#define K1_REAL  228      // 2*FEAT + NMU
#define K1_PAD   256      // padded K for layer 1 (8 steps of 32)
#define HID      128
#define ODIM     64
#define K2       128
#define MTILE    64       // edges per block
#define LDA1     264      // A-tile leading dim (bf16 elems): 256 + 8 pad
#define LDH      136      // H-tile leading dim: 128 + 8 pad

typedef __bf16 bf16x8 __attribute__((ext_vector_type(8)));
typedef __bf16 bf16x4 __attribute__((ext_vector_type(4)));
typedef float  fx4    __attribute__((ext_vector_type(4)));

// Pack W1 [HID=128, K1_REAL=228] fp32 -> bf16 fragment-order:
// B1[((kk*4+q)*128 + n)*8 + j] = W1[n][kk*32 + q*8 + j]  (0 if k >= 228)
__global__ void pack_w1(const float* __restrict__ W1, __bf16* __restrict__ B1) {
    int i = blockIdx.x * 256 + threadIdx.x;     // 0..32767
    int j  = i & 7;
    int n  = (i >> 3) & 127;
    int qk = i >> 10;                           // kk*4 + q, 0..31
    int k  = (qk >> 2) * 32 + (qk & 3) * 8 + j;
    float v = (k < K1_REAL) ? W1[n * K1_REAL + k] : 0.0f;
    B1[i] = (__bf16)v;
}

// Pack W2 [ODIM=64, K2=128] fp32 -> bf16 fragment-order:
// B2[((kk*4+q)*64 + n)*8 + j] = W2[n][kk*32 + q*8 + j]
__global__ void pack_w2(const float* __restrict__ W2, __bf16* __restrict__ B2) {
    int i = blockIdx.x * 256 + threadIdx.x;     // 0..8191
    int j  = i & 7;
    int n  = (i >> 3) & 63;
    int qk = i >> 9;                            // 0..15
    int k  = (qk >> 2) * 32 + (qk & 3) * 8 + j;
    B2[i] = (__bf16)W2[n * K2 + k];
}

__global__ __launch_bounds__(256)
void edges_fused(const float* __restrict__ h,
                 const int*   __restrict__ src,
                 const int*   __restrict__ dst,
                 const float* __restrict__ enorm,
                 const float* __restrict__ mu,
                 const __bf16* __restrict__ B1,
                 const __bf16* __restrict__ B2,
                 float* __restrict__ out) {
    __shared__ __bf16 Atile[MTILE * LDA1];   // 33792 B
    __shared__ __bf16 Htile[MTILE * LDH];    // 17408 B

    const int tid = threadIdx.x;
    const int e0  = blockIdx.x * MTILE;

    // ---- Stage 1: build A-tile (64 rows x [h_src(64) | h_dst(64) | rbf(100) | 0-pad(28)]) ----
    {
        // Gather: 4 threads per row; p=0,1 -> src halves, p=2,3 -> dst halves
        int r = tid >> 2, p = tid & 3;
        int e = e0 + r;
        int node = (p < 2) ? src[e] : dst[e];
        int half = p & 1;
        const float4* hp = (const float4*)(h + (size_t)node * FEAT + half * 32);
        __bf16* ap = &Atile[r * LDA1 + (p >> 1) * FEAT + half * 32];
#pragma unroll
        for (int i = 0; i < 8; ++i) {
            float4 v = hp[i];
            bf16x4 o = { (__bf16)v.x, (__bf16)v.y, (__bf16)v.z, (__bf16)v.w };
            *(bf16x4*)(ap + i * 4) = o;
        }
    }
    {
        // RBF: 4 threads per row, 25 mus each; then zero-pad cols 228..255
        int r = tid >> 2, g = tid & 3;
        float d = enorm[e0 + r];
        __bf16* ap = &Atile[r * LDA1 + 2 * FEAT];
        int j0 = g * 25;
#pragma unroll
        for (int jj = 0; jj < 25; ++jj) {
            int j = j0 + jj;
            float t = mu[j] - d;
            ap[j] = (__bf16)__expf(-10.0f * t * t);
        }
        __bf16* zp = &Atile[r * LDA1 + K1_REAL + g * 7];
#pragma unroll
        for (int c = 0; c < 7; ++c) zp[c] = (__bf16)0.0f;
    }
    __syncthreads();

    const int lane = tid & 63;
    const int w    = tid >> 6;    // wave 0..3: owns N-tiles {2w, 2w+1} of layer 1
    const int ln   = lane & 15;
    const int q    = lane >> 4;

    // ---- Layer 1: [64 x 256] @ [256 x 128] -> silu -> Htile ----
    fx4 acc[4][2];
#pragma unroll
    for (int mt = 0; mt < 4; ++mt)
#pragma unroll
        for (int ntl = 0; ntl < 2; ++ntl)
            acc[mt][ntl] = (fx4){0.f, 0.f, 0.f, 0.f};

    const bf16x8* pB1 = (const bf16x8*)B1;
#pragma unroll
    for (int kk = 0; kk < 8; ++kk) {
        const int kof = kk * 32 + q * 8;
        bf16x8 a[4];
#pragma unroll
        for (int mt = 0; mt < 4; ++mt)
            a[mt] = *(const bf16x8*)&Atile[(mt * 16 + ln) * LDA1 + kof];
        bf16x8 b[2];
#pragma unroll
        for (int ntl = 0; ntl < 2; ++ntl)
            b[ntl] = pB1[(kk * 4 + q) * 128 + (w * 2 + ntl) * 16 + ln];
#pragma unroll
        for (int mt = 0; mt < 4; ++mt)
#pragma unroll
            for (int ntl = 0; ntl < 2; ++ntl)
                acc[mt][ntl] = __builtin_amdgcn_mfma_f32_16x16x32_bf16(
                    a[mt], b[ntl], acc[mt][ntl], 0, 0, 0);
    }

    // SiLU, convert to bf16, write H-tile.
    // C/D layout: col = lane&15, row = q*4 + reg  (within each 16x16 tile)
#pragma unroll
    for (int mt = 0; mt < 4; ++mt) {
#pragma unroll
        for (int ntl = 0; ntl < 2; ++ntl) {
#pragma unroll
            for (int r = 0; r < 4; ++r) {
                float z = acc[mt][ntl][r];
                float s = z / (1.0f + __expf(-z));
                int row = mt * 16 + q * 4 + r;
                int col = (w * 2 + ntl) * 16 + ln;
                Htile[row * LDH + col] = (__bf16)s;
            }
        }
    }
    __syncthreads();

    // ---- Layer 2: [64 x 128] @ [128 x 64] -> out ----
    fx4 acc2[4];
#pragma unroll
    for (int mt = 0; mt < 4; ++mt) acc2[mt] = (fx4){0.f, 0.f, 0.f, 0.f};

    const bf16x8* pB2 = (const bf16x8*)B2;
#pragma unroll
    for (int kk = 0; kk < 4; ++kk) {
        const int kof = kk * 32 + q * 8;
        bf16x8 b2 = pB2[(kk * 4 + q) * 64 + w * 16 + ln];
#pragma unroll
        for (int mt = 0; mt < 4; ++mt) {
            bf16x8 a2 = *(const bf16x8*)&Htile[(mt * 16 + ln) * LDH + kof];
            acc2[mt] = __builtin_amdgcn_mfma_f32_16x16x32_bf16(a2, b2, acc2[mt], 0, 0, 0);
        }
    }

    // Store: wave w owns output cols [16w, 16w+16)
#pragma unroll
    for (int mt = 0; mt < 4; ++mt) {
#pragma unroll
        for (int r = 0; r < 4; ++r) {
            int row = mt * 16 + q * 4 + r;
            int col = w * 16 + ln;
            out[(size_t)(e0 + row) * ODIM + col] = acc2[mt][r];
        }
    }
}

extern "C" void kernel_launch(void* const* d_in, const int* in_sizes, int n_in,
                              void* d_out, int out_size, void* d_ws, size_t ws_size,
                              hipStream_t stream) {
    const float* h   = (const float*)d_in[0];
    const int*   src = (const int*)d_in[1];
    const int*   dst = (const int*)d_in[2];
    const float* en  = (const float*)d_in[3];
    const float* mu  = (const float*)d_in[4];
    const float* W1  = (const float*)d_in[5];
    const float* W2  = (const float*)d_in[6];

    __bf16* B1 = (__bf16*)d_ws;                          // 32768 bf16 = 64 KB
    __bf16* B2 = (__bf16*)((char*)d_ws + 65536);         // 8192 bf16  = 16 KB

    pack_w1<<<128, 256, 0, stream>>>(W1, B1);
    pack_w2<<<32, 256, 0, stream>>>(W2, B2);

    const int E = in_sizes[1];                 // 800000, divisible by MTILE
    const int nblocks = E / MTILE;             // 12500
    edges_fused<<<nblocks, 256, 0, stream>>>(h, src, dst, en, mu, B1, B2, (float*)d_out);
}